// Round 1
// baseline (223.001 us; speedup 1.0000x reference)
//
#include <hip/hip_runtime.h>
#include <math.h>

#define HOP 128
#define NFFT 256
#define T_LEN 640000
#define N_FRAMES 5001
#define TOTAL_FRAMES (64 * N_FRAMES)
#define NBINS 129
#define FPB 16   // frames per block (16 threads per frame, 256 threads)

__global__ __launch_bounds__(256) void loudness_kernel(const float* __restrict__ x,
                                                       float* __restrict__ out) {
    // cos/sin(2*pi*m/16) — compile-time constants; indices below are
    // compile-time after full unroll, so these fold to immediates (no LDS).
    constexpr float C16[16] = {
        1.0f,  0.9238795325112867f,  0.7071067811865476f,  0.3826834323650898f,
        0.0f, -0.3826834323650898f, -0.7071067811865476f, -0.9238795325112867f,
       -1.0f, -0.9238795325112867f, -0.7071067811865476f, -0.3826834323650898f,
        0.0f,  0.3826834323650898f,  0.7071067811865476f,  0.9238795325112867f};
    constexpr float S16[16] = {
        0.0f,  0.3826834323650898f,  0.7071067811865476f,  0.9238795325112867f,
        1.0f,  0.9238795325112867f,  0.7071067811865476f,  0.3826834323650898f,
        0.0f, -0.3826834323650898f, -0.7071067811865476f, -0.9238795325112867f,
       -1.0f, -0.9238795325112867f, -0.7071067811865476f, -0.3826834323650898f};

    __shared__ float s_tw_re[256];        // [k1][n1] cos(2pi n1 k1/256)
    __shared__ float s_tw_im[256];        // [k1][n1] -sin(2pi n1 k1/256)
    __shared__ float s_win[256];          // Hann window
    __shared__ float s_aw[NBINS];         // A-weighting dB
    __shared__ float s_cre[FPB][16 * 17]; // transpose buffer (pad 17: conflict-free)
    __shared__ float s_cim[FPB][16 * 17];

    const int tid = threadIdx.x;

    // ---- per-block table generation ----
    {
        const int kk = tid >> 4, nn = tid & 15;
        const float TWOPI_256 = 0.02454369260617026f; // 2*pi/256
        float s, c;
        sincosf((float)(kk * nn) * TWOPI_256, &s, &c); // product symmetric: layout-agnostic
        s_tw_re[tid] = c;
        s_tw_im[tid] = -s;
        s_win[tid] = 0.5f - 0.5f * cosf((float)tid * TWOPI_256);
        if (tid < NBINS) {
            float f = (float)tid * 62.5f; // k * SR/NFFT
            float f2 = f * f;
            const float c0 = 12194.217f * 12194.217f;
            const float c1 = 20.598997f * 20.598997f;
            const float c2 = 107.65265f * 107.65265f;
            const float c3 = 737.86223f * 737.86223f;
            float w = 2.0f + 20.0f * (log10f(c0) + 2.0f * log10f(fmaxf(f2, 1e-30f))
                     - log10f(f2 + c0) - log10f(f2 + c1)
                     - 0.5f * log10f(f2 + c2) - 0.5f * log10f(f2 + c3));
            s_aw[tid] = fmaxf(w, -80.0f);
        }
    }
    __syncthreads();

    const int g  = blockIdx.x * FPB + (tid >> 4); // global frame id (exact: 320064/16)
    const int n1 = tid & 15;                      // stage-1 role n1; stage-2 role k1
    const int fr = tid >> 4;                      // frame slot in block
    const int b  = g / N_FRAMES;
    const int f  = g - b * N_FRAMES;
    const float* __restrict__ xb = x + (size_t)b * T_LEN;

    // ---- load + window (reflect padding), n = n1 + 16*n2 ----
    float xw[16];
    const int base = f * HOP - HOP + n1;
#pragma unroll
    for (int n2 = 0; n2 < 16; ++n2) {
        int j = base + 16 * n2;
        j = (j < 0) ? -j : j;
        j = (j >= T_LEN) ? (2 * T_LEN - 2 - j) : j;
        xw[n2] = xb[j] * s_win[n1 + 16 * n2];
    }

    // ---- stage 1: DFT-16 over n2 (real input) + twiddle e^{-2pi i n1 k1/256} ----
    float Are[16], Aim[16];
#pragma unroll
    for (int k1 = 0; k1 < 16; ++k1) {
        float re = 0.f, im = 0.f;
#pragma unroll
        for (int n2 = 0; n2 < 16; ++n2) {
            const int m = (k1 * n2) & 15;
            re += xw[n2] * C16[m];
            im -= xw[n2] * S16[m];
        }
        const float tr = s_tw_re[k1 * 16 + n1];
        const float ti = s_tw_im[k1 * 16 + n1];
        Are[k1] = re * tr - im * ti;
        Aim[k1] = re * ti + im * tr;
    }

    // ---- transpose within frame via LDS ----
#pragma unroll
    for (int k1 = 0; k1 < 16; ++k1) {
        s_cre[fr][n1 * 17 + k1] = Are[k1];
        s_cim[fr][n1 * 17 + k1] = Aim[k1];
    }
    __syncthreads();

    float br[16], bi[16];
#pragma unroll
    for (int m = 0; m < 16; ++m) {
        br[m] = s_cre[fr][m * 17 + n1];
        bi[m] = s_cim[fr][m * 17 + n1];
    }

    // ---- stage 2: DFT-16 over n1; bins k = k1 + 16*k2, keep k <= 128 ----
    float ssum = 0.f;
#pragma unroll
    for (int k2 = 0; k2 < 9; ++k2) {
        float re = 0.f, im = 0.f;
#pragma unroll
        for (int m = 0; m < 16; ++m) {
            const int t = (k2 * m) & 15;
            const float wr = C16[t];
            const float wi = -S16[t];
            re += br[m] * wr - bi[m] * wi;
            im += br[m] * wi + bi[m] * wr;
        }
        const int bin = n1 + 16 * k2;
        if (bin < NBINS) {
            const float mag = sqrtf(re * re + im * im);
            ssum += logf(mag + 1e-7f) + s_aw[bin];
        }
    }

    // ---- reduce across the 16 lanes of this frame ----
    ssum += __shfl_xor(ssum, 1);
    ssum += __shfl_xor(ssum, 2);
    ssum += __shfl_xor(ssum, 4);
    ssum += __shfl_xor(ssum, 8);

    if (n1 == 0) out[g] = ssum * (1.0f / 129.0f);
}

extern "C" void kernel_launch(void* const* d_in, const int* in_sizes, int n_in,
                              void* d_out, int out_size, void* d_ws, size_t ws_size,
                              hipStream_t stream) {
    const float* x = (const float*)d_in[0];
    float* out = (float*)d_out;
    loudness_kernel<<<TOTAL_FRAMES / FPB, 256, 0, stream>>>(x, out);
}

// Round 2
// 144.027 us; speedup vs baseline: 1.5483x; 1.5483x over previous
//
#include <hip/hip_runtime.h>
#include <math.h>

#define HOP 128
#define NFFT 256
#define T_LEN 640000
#define N_FRAMES 5001
#define TOTAL_FRAMES (64 * N_FRAMES)
#define NBINS 129
#define FPB 16   // frames per block (16 threads per frame, 256 threads)

__global__ __launch_bounds__(256) void loudness_kernel(const float* __restrict__ x,
                                                       float* __restrict__ out) {
    // cos/sin(2*pi*m/16) — compile-time constants; indices are compile-time
    // after full unroll, so these fold to immediates (0/±1 multiplies vanish).
    constexpr float C16[16] = {
        1.0f,  0.9238795325112867f,  0.7071067811865476f,  0.3826834323650898f,
        0.0f, -0.3826834323650898f, -0.7071067811865476f, -0.9238795325112867f,
       -1.0f, -0.9238795325112867f, -0.7071067811865476f, -0.3826834323650898f,
        0.0f,  0.3826834323650898f,  0.7071067811865476f,  0.9238795325112867f};
    constexpr float S16[16] = {
        0.0f,  0.3826834323650898f,  0.7071067811865476f,  0.9238795325112867f,
        1.0f,  0.9238795325112867f,  0.7071067811865476f,  0.3826834323650898f,
        0.0f, -0.3826834323650898f, -0.7071067811865476f, -0.9238795325112867f,
       -1.0f, -0.9238795325112867f, -0.7071067811865476f, -0.3826834323650898f};

    __shared__ float s_tw_re[256];        // [k1][n1] cos(2pi n1 k1/256)
    __shared__ float s_tw_im[256];        // [k1][n1] -sin(2pi n1 k1/256)
    __shared__ float s_win[256];          // Hann window
    __shared__ float s_aw[NBINS];         // A-weighting dB
    __shared__ float s_cre[FPB][16 * 17]; // transpose buffer (pad 17: conflict-free)
    __shared__ float s_cim[FPB][16 * 17];

    const int tid = threadIdx.x;

    // ---- per-block table generation ----
    {
        const int kk = tid >> 4, nn = tid & 15;
        const float TWOPI_256 = 0.02454369260617026f; // 2*pi/256
        float s, c;
        sincosf((float)(kk * nn) * TWOPI_256, &s, &c);
        s_tw_re[tid] = c;
        s_tw_im[tid] = -s;
        s_win[tid] = 0.5f - 0.5f * cosf((float)tid * TWOPI_256);
        if (tid < NBINS) {
            float f = (float)tid * 62.5f; // k * SR/NFFT
            float f2 = f * f;
            const float c0 = 12194.217f * 12194.217f;
            const float c1 = 20.598997f * 20.598997f;
            const float c2 = 107.65265f * 107.65265f;
            const float c3 = 737.86223f * 737.86223f;
            float w = 2.0f + 20.0f * (log10f(c0) + 2.0f * log10f(fmaxf(f2, 1e-30f))
                     - log10f(f2 + c0) - log10f(f2 + c1)
                     - 0.5f * log10f(f2 + c2) - 0.5f * log10f(f2 + c3));
            s_aw[tid] = fmaxf(w, -80.0f);
        }
    }
    __syncthreads();

    const int g  = blockIdx.x * FPB + (tid >> 4); // global frame id (exact: 320064/16)
    const int n1 = tid & 15;                      // stage-1 role n1; stage-2 role k1
    const int fr = tid >> 4;                      // frame slot in block
    const int b  = g / N_FRAMES;
    const int f  = g - b * N_FRAMES;
    const float* __restrict__ xb = x + (size_t)b * T_LEN;

    // ---- load + window (reflect padding), n = n1 + 16*n2 ----
    float xw[16];
    const int base = f * HOP - HOP + n1;
    if (f >= 1 && f <= 4998) {
        // interior: no reflection possible (base >= 0, base+240 < T_LEN)
        const float* __restrict__ xp = xb + base;
#pragma unroll
        for (int n2 = 0; n2 < 16; ++n2) {
            xw[n2] = xp[16 * n2] * s_win[n1 + 16 * n2];
        }
    } else {
#pragma unroll
        for (int n2 = 0; n2 < 16; ++n2) {
            int j = base + 16 * n2;
            j = (j < 0) ? -j : j;
            j = (j >= T_LEN) ? (2 * T_LEN - 2 - j) : j;
            xw[n2] = xb[j] * s_win[n1 + 16 * n2];
        }
    }

    // ---- stage 1: real-input DFT-16 over n2, Hermitian-symmetric ----
    // raw[k], k=0..8 computed; raw[16-k] = conj(raw[k]).
    float r0 = 0.f, r8 = 0.f;
#pragma unroll
    for (int n2 = 0; n2 < 16; ++n2) {
        r0 += xw[n2];
        r8 += (n2 & 1) ? -xw[n2] : xw[n2];
    }
    float rre[8], rim[8]; // k1 = 1..7 at indices 1..7 (index 0 unused)
#pragma unroll
    for (int k1 = 1; k1 <= 7; ++k1) {
        float re = 0.f, im = 0.f;
#pragma unroll
        for (int n2 = 0; n2 < 16; ++n2) {
            const int m = (k1 * n2) & 15;
            re += xw[n2] * C16[m];
            im -= xw[n2] * S16[m];
        }
        rre[k1] = re;
        rim[k1] = im;
    }

    // ---- twiddle by e^{-2pi i n1 k1/256} ----
    float Are[16], Aim[16];
    Are[0] = r0;      // tw(k1=0, n1) = 1
    Aim[0] = 0.f;
#pragma unroll
    for (int k1 = 1; k1 <= 15; ++k1) {
        float rr, ri;
        if (k1 < 8)       { rr = rre[k1];      ri = rim[k1]; }
        else if (k1 == 8) { rr = r8;           ri = 0.f; }
        else              { rr = rre[16 - k1]; ri = -rim[16 - k1]; }
        const float tr = s_tw_re[k1 * 16 + n1];
        const float ti = s_tw_im[k1 * 16 + n1];
        Are[k1] = rr * tr - ri * ti;
        Aim[k1] = rr * ti + ri * tr;
    }

    // ---- transpose within frame via LDS ----
#pragma unroll
    for (int k1 = 0; k1 < 16; ++k1) {
        s_cre[fr][n1 * 17 + k1] = Are[k1];
        s_cim[fr][n1 * 17 + k1] = Aim[k1];
    }
    __syncthreads();

    float br[16], bi[16];
#pragma unroll
    for (int m = 0; m < 16; ++m) {
        br[m] = s_cre[fr][m * 17 + n1];
        bi[m] = s_cim[fr][m * 17 + n1];
    }

    // ---- stage 2: DFT-16 over n1; bins k = k1 + 16*k2, k2=0..7 (bins 0..127) ----
    const float HALF_LN2 = 0.34657359027997264f; // 0.5 * ln(2)
    float ssum = 0.f;
#pragma unroll
    for (int k2 = 0; k2 < 8; ++k2) {
        float re = 0.f, im = 0.f;
#pragma unroll
        for (int m = 0; m < 16; ++m) {
            const int t = (k2 * m) & 15;
            const float wr = C16[t];
            const float wi = -S16[t];
            re += br[m] * wr - bi[m] * wi;
            im += br[m] * wi + bi[m] * wr;
        }
        const int bin = n1 + 16 * k2;
        const float mag2 = re * re + im * im;
        // log(mag+1e-7) ~= 0.5*ln(mag2+1e-14); exact when mag >> 1e-7
        ssum += HALF_LN2 * __builtin_amdgcn_logf(mag2 + 1e-14f) + s_aw[bin];
    }

    // ---- bin 128: X[128] = sum_{n1} (-1)^{n1} * r0[n1] (real) ----
    float v = (n1 & 1) ? -r0 : r0;
    v += __shfl_xor(v, 1);
    v += __shfl_xor(v, 2);
    v += __shfl_xor(v, 4);
    v += __shfl_xor(v, 8);
    const float term128 = HALF_LN2 * __builtin_amdgcn_logf(v * v + 1e-14f) + s_aw[128];

    // ---- reduce 128 bins across the 16 lanes of this frame, add bin 128 ----
    ssum += __shfl_xor(ssum, 1);
    ssum += __shfl_xor(ssum, 2);
    ssum += __shfl_xor(ssum, 4);
    ssum += __shfl_xor(ssum, 8);

    if (n1 == 0) out[g] = (ssum + term128) * (1.0f / 129.0f);
}

extern "C" void kernel_launch(void* const* d_in, const int* in_sizes, int n_in,
                              void* d_out, int out_size, void* d_ws, size_t ws_size,
                              hipStream_t stream) {
    const float* x = (const float*)d_in[0];
    float* out = (float*)d_out;
    loudness_kernel<<<TOTAL_FRAMES / FPB, 256, 0, stream>>>(x, out);
}

// Round 3
// 87.388 us; speedup vs baseline: 2.5519x; 1.6481x over previous
//
#include <hip/hip_runtime.h>
#include <math.h>

#define HOP 128
#define NFFT 256
#define T_LEN 640000
#define N_FRAMES 5001
#define TOTAL_FRAMES (64 * N_FRAMES)
#define NBINS 129
#define FPB 16   // frames per block (16 threads per frame, 256 threads)

__global__ __launch_bounds__(256) void loudness_kernel(const float* __restrict__ x,
                                                       float* __restrict__ out) {
    // cos/sin(2*pi*m/16) — compile-time constants (indices compile-time after unroll)
    constexpr float C16[16] = {
        1.0f,  0.9238795325112867f,  0.7071067811865476f,  0.3826834323650898f,
        0.0f, -0.3826834323650898f, -0.7071067811865476f, -0.9238795325112867f,
       -1.0f, -0.9238795325112867f, -0.7071067811865476f, -0.3826834323650898f,
        0.0f,  0.3826834323650898f,  0.7071067811865476f,  0.9238795325112867f};
    constexpr float S16[16] = {
        0.0f,  0.3826834323650898f,  0.7071067811865476f,  0.9238795325112867f,
        1.0f,  0.9238795325112867f,  0.7071067811865476f,  0.3826834323650898f,
        0.0f, -0.3826834323650898f, -0.7071067811865476f, -0.9238795325112867f,
       -1.0f, -0.9238795325112867f, -0.7071067811865476f, -0.3826834323650898f};
    const float R2 = 0.7071067811865476f;
    const float c1 = 0.9238795325112867f, s1 = 0.3826834323650898f;
    const float c3 = 0.3826834323650898f, s3 = 0.9238795325112867f;

    __shared__ float s_tw_re[256];        // [k1][n1] cos(2pi n1 k1/256)
    __shared__ float s_tw_im[256];        // [k1][n1] -sin(2pi n1 k1/256)
    __shared__ float s_win[256];          // Hann window
    __shared__ float s_aw[NBINS];         // A-weighting dB
    __shared__ float s_cre[FPB][16 * 17]; // transpose buffer (pad 17: conflict-free)
    __shared__ float s_cim[FPB][16 * 17];

    const int tid = threadIdx.x;

    // ---- per-block table generation ----
    {
        const int kk = tid >> 4, nn = tid & 15;
        const float TWOPI_256 = 0.02454369260617026f; // 2*pi/256
        float s, c;
        sincosf((float)(kk * nn) * TWOPI_256, &s, &c);
        s_tw_re[tid] = c;
        s_tw_im[tid] = -s;
        s_win[tid] = 0.5f - 0.5f * cosf((float)tid * TWOPI_256);
        if (tid < NBINS) {
            float f = (float)tid * 62.5f; // k * SR/NFFT
            float f2 = f * f;
            const float a0 = 12194.217f * 12194.217f;
            const float a1 = 20.598997f * 20.598997f;
            const float a2 = 107.65265f * 107.65265f;
            const float a3 = 737.86223f * 737.86223f;
            float w = 2.0f + 20.0f * (log10f(a0) + 2.0f * log10f(fmaxf(f2, 1e-30f))
                     - log10f(f2 + a0) - log10f(f2 + a1)
                     - 0.5f * log10f(f2 + a2) - 0.5f * log10f(f2 + a3));
            s_aw[tid] = fmaxf(w, -80.0f);
        }
    }
    __syncthreads();

    const int g  = blockIdx.x * FPB + (tid >> 4); // global frame id
    const int n1 = tid & 15;                      // stage-1 role n1; stage-2 role k1
    const int fr = tid >> 4;                      // frame slot in block
    const int b  = g / N_FRAMES;
    const int f  = g - b * N_FRAMES;
    const float* __restrict__ xb = x + (size_t)b * T_LEN;

    // ---- load + window (reflect padding), n = n1 + 16*n2 ----
    float xw[16];
    const int base = f * HOP - HOP + n1;
    if (f >= 1 && f <= 4998) {
        const float* __restrict__ xp = xb + base;
#pragma unroll
        for (int n2 = 0; n2 < 16; ++n2) {
            xw[n2] = xp[16 * n2] * s_win[n1 + 16 * n2];
        }
    } else {
#pragma unroll
        for (int n2 = 0; n2 < 16; ++n2) {
            int j = base + 16 * n2;
            j = (j < 0) ? -j : j;
            j = (j >= T_LEN) ? (2 * T_LEN - 2 - j) : j;
            xw[n2] = xb[j] * s_win[n1 + 16 * n2];
        }
    }

    // ---- stage 1: real DFT-16 over n2, cos/sin folded (Hermitian) ----
    // p[n] = xw[n]+xw[16-n], q[n] = xw[n]-xw[16-n], n=1..7
    float p[8], q[8];
#pragma unroll
    for (int n = 1; n <= 7; ++n) { p[n] = xw[n] + xw[16 - n]; q[n] = xw[n] - xw[16 - n]; }
    const float bse = xw[0] + xw[8];
    const float se  = p[2] + p[4] + p[6];
    const float so  = p[1] + p[3] + p[5] + p[7];
    const float r0  = bse + se + so;   // raw[0]
    const float r8  = bse + se - so;   // raw[8]
    float rre[8], rim[8];              // raw[k1], k1=1..7 (index 0 unused)
#pragma unroll
    for (int k1 = 1; k1 <= 7; ++k1) {
        float re = xw[0] + ((k1 & 1) ? -xw[8] : xw[8]);
        float im = 0.f;
#pragma unroll
        for (int n = 1; n <= 7; ++n) {
            const int m = (k1 * n) & 15;
            re += p[n] * C16[m];
            im -= q[n] * S16[m];
        }
        rre[k1] = re;
        rim[k1] = im;
    }

    // ---- twiddle by e^{-2pi i n1 k1/256}, Hermitian reconstruction ----
    float Are[16], Aim[16];
    Are[0] = r0;
    Aim[0] = 0.f;
#pragma unroll
    for (int k1 = 1; k1 <= 15; ++k1) {
        float rr, ri;
        if (k1 < 8)       { rr = rre[k1];      ri = rim[k1]; }
        else if (k1 == 8) { rr = r8;           ri = 0.f; }
        else              { rr = rre[16 - k1]; ri = -rim[16 - k1]; }
        const float tr = s_tw_re[k1 * 16 + n1];
        const float ti = s_tw_im[k1 * 16 + n1];
        Are[k1] = rr * tr - ri * ti;
        Aim[k1] = rr * ti + ri * tr;
    }

    // ---- transpose within frame via LDS ----
#pragma unroll
    for (int k1 = 0; k1 < 16; ++k1) {
        s_cre[fr][n1 * 17 + k1] = Are[k1];
        s_cim[fr][n1 * 17 + k1] = Aim[k1];
    }
    __syncthreads();

    float br[16], bi[16];
#pragma unroll
    for (int m = 0; m < 16; ++m) {
        br[m] = s_cre[fr][m * 17 + n1];
        bi[m] = s_cim[fr][m * 17 + n1];
    }

    // ---- stage 2: radix-2 DIF FFT-16 over m; Y[k2] = sum br[m] W16^(m k2) ----
    // Stage A: span 8, twiddle W16^j on difference
#pragma unroll
    for (int j = 0; j < 8; ++j) {
        float ur = br[j], ui = bi[j], vr = br[j + 8], vi = bi[j + 8];
        br[j] = ur + vr; bi[j] = ui + vi;
        float dr = ur - vr, di = ui - vi;
        float or_, oi_;
        if      (j == 0) { or_ = dr;                 oi_ = di; }
        else if (j == 1) { or_ =  dr * c1 + di * s1; oi_ =  di * c1 - dr * s1; }
        else if (j == 2) { or_ = R2 * (dr + di);     oi_ = R2 * (di - dr); }
        else if (j == 3) { or_ =  dr * c3 + di * s3; oi_ =  di * c3 - dr * s3; }
        else if (j == 4) { or_ = di;                 oi_ = -dr; }
        else if (j == 5) { or_ = -dr * c3 + di * s3; oi_ = -di * c3 - dr * s3; }
        else if (j == 6) { or_ = R2 * (di - dr);     oi_ = -R2 * (dr + di); }
        else             { or_ = -dr * c1 + di * s1; oi_ = -di * c1 - dr * s1; }
        br[j + 8] = or_; bi[j + 8] = oi_;
    }
    // Stage B: span 4, twiddles {1, R-iR, -i, -R-iR}
#pragma unroll
    for (int h = 0; h <= 8; h += 8) {
#pragma unroll
        for (int j = 0; j < 4; ++j) {
            float ur = br[h + j], ui = bi[h + j], vr = br[h + j + 4], vi = bi[h + j + 4];
            br[h + j] = ur + vr; bi[h + j] = ui + vi;
            float dr = ur - vr, di = ui - vi;
            float or_, oi_;
            if      (j == 0) { or_ = dr;             oi_ = di; }
            else if (j == 1) { or_ = R2 * (dr + di); oi_ = R2 * (di - dr); }
            else if (j == 2) { or_ = di;             oi_ = -dr; }
            else             { or_ = R2 * (di - dr); oi_ = -R2 * (dr + di); }
            br[h + j + 4] = or_; bi[h + j + 4] = oi_;
        }
    }
    // Stage C: span 2, twiddles {1, -i}
#pragma unroll
    for (int gg = 0; gg < 16; gg += 4) {
        {
            float ur = br[gg], ui = bi[gg], vr = br[gg + 2], vi = bi[gg + 2];
            br[gg] = ur + vr;     bi[gg] = ui + vi;
            br[gg + 2] = ur - vr; bi[gg + 2] = ui - vi;
        }
        {
            float ur = br[gg + 1], ui = bi[gg + 1], vr = br[gg + 3], vi = bi[gg + 3];
            br[gg + 1] = ur + vr; bi[gg + 1] = ui + vi;
            float dr = ur - vr, di = ui - vi;
            br[gg + 3] = di; bi[gg + 3] = -dr;
        }
    }
    // Stage D: only even outputs (bins k2=0..7); position 2t holds k2=bitrev3(t)
    const float HALF_LN2 = 0.34657359027997264f; // 0.5*ln2; v_log_f32 is log2
    constexpr int K2MAP[8] = {0, 4, 2, 6, 1, 5, 3, 7};
    float ssum = 0.f;
#pragma unroll
    for (int t = 0; t < 8; ++t) {
        const float Yr = br[2 * t] + br[2 * t + 1];
        const float Yi = bi[2 * t] + bi[2 * t + 1];
        const int bin = n1 + 16 * K2MAP[t];
        const float mag2 = Yr * Yr + Yi * Yi;
        // log(mag+1e-7) ~= 0.5*ln2*log2(mag2+1e-14)
        ssum += HALF_LN2 * __builtin_amdgcn_logf(mag2 + 1e-14f) + s_aw[bin];
    }

    // ---- bin 128: X[128] = sum_{n1} (-1)^{n1} * r0[n1] (real) ----
    float v = (n1 & 1) ? -r0 : r0;
    v += __shfl_xor(v, 1);
    v += __shfl_xor(v, 2);
    v += __shfl_xor(v, 4);
    v += __shfl_xor(v, 8);
    const float term128 = HALF_LN2 * __builtin_amdgcn_logf(v * v + 1e-14f) + s_aw[128];

    // ---- reduce 128 bins across the 16 lanes of this frame ----
    ssum += __shfl_xor(ssum, 1);
    ssum += __shfl_xor(ssum, 2);
    ssum += __shfl_xor(ssum, 4);
    ssum += __shfl_xor(ssum, 8);

    if (n1 == 0) out[g] = (ssum + term128) * (1.0f / 129.0f);
}

extern "C" void kernel_launch(void* const* d_in, const int* in_sizes, int n_in,
                              void* d_out, int out_size, void* d_ws, size_t ws_size,
                              hipStream_t stream) {
    const float* x = (const float*)d_in[0];
    float* out = (float*)d_out;
    loudness_kernel<<<TOTAL_FRAMES / FPB, 256, 0, stream>>>(x, out);
}

// Round 4
// 77.112 us; speedup vs baseline: 2.8919x; 1.1333x over previous
//
#include <hip/hip_runtime.h>
#include <math.h>

#define HOP 128
#define T_LEN 640000
#define N_FRAMES 5001
#define TOTAL_FRAMES (64 * N_FRAMES)
#define NBINS 129
#define FPB 16   // frames per block (16 threads per frame, 256 threads)

typedef float v2f __attribute__((ext_vector_type(2)));

static __device__ __forceinline__ v2f mk2(float a, float b) { v2f r; r.x = a; r.y = b; return r; }
static __device__ __forceinline__ v2f sp(float s) { v2f r; r.x = s; r.y = s; return r; }

__global__ __launch_bounds__(256) void loudness_kernel(const float* __restrict__ x,
                                                       float* __restrict__ out) {
    constexpr float C16[16] = {
        1.0f,  0.9238795325112867f,  0.7071067811865476f,  0.3826834323650898f,
        0.0f, -0.3826834323650898f, -0.7071067811865476f, -0.9238795325112867f,
       -1.0f, -0.9238795325112867f, -0.7071067811865476f, -0.3826834323650898f,
        0.0f,  0.3826834323650898f,  0.7071067811865476f,  0.9238795325112867f};
    constexpr float S16[16] = {
        0.0f,  0.3826834323650898f,  0.7071067811865476f,  0.9238795325112867f,
        1.0f,  0.9238795325112867f,  0.7071067811865476f,  0.3826834323650898f,
        0.0f, -0.3826834323650898f, -0.7071067811865476f, -0.9238795325112867f,
       -1.0f, -0.9238795325112867f, -0.7071067811865476f, -0.3826834323650898f};
    const float R2  = 0.7071067811865476f;
    const float c1v = 0.9238795325112867f, s1v = 0.3826834323650898f;
    const float c3v = 0.3826834323650898f, s3v = 0.9238795325112867f;

    __shared__ float4 s_tw4[256];     // (c, -s, s, c) at [k1*16+n1]      4096 B
    __shared__ v2f    s_c[FPB][273];  // transpose buf, row stride 17    34944 B
    __shared__ float  s_win[256];     //                                  1024 B
    __shared__ float  s_aw[NBINS];    //                                   516 B  -> 40580 <= 40960 (4 blk/CU)

    const int tid = threadIdx.x;

    // ---- per-block table generation ----
    {
        const int kk = tid >> 4, nn = tid & 15;
        const float TWOPI_256 = 0.02454369260617026f; // 2*pi/256
        float s, c;
        sincosf((float)(kk * nn) * TWOPI_256, &s, &c);
        s_tw4[tid] = make_float4(c, -s, s, c);
        s_win[tid] = 0.5f - 0.5f * cosf((float)tid * TWOPI_256);
        if (tid < NBINS) {
            float fq = (float)tid * 62.5f; // k * SR/NFFT
            float f2 = fq * fq;
            const float a0 = 12194.217f * 12194.217f;
            const float a1 = 20.598997f * 20.598997f;
            const float a2 = 107.65265f * 107.65265f;
            const float a3 = 737.86223f * 737.86223f;
            float w = 2.0f + 20.0f * (log10f(a0) + 2.0f * log10f(fmaxf(f2, 1e-30f))
                     - log10f(f2 + a0) - log10f(f2 + a1)
                     - 0.5f * log10f(f2 + a2) - 0.5f * log10f(f2 + a3));
            s_aw[tid] = fmaxf(w, -80.0f);
        }
    }
    __syncthreads();

    const int g  = blockIdx.x * FPB + (tid >> 4); // global frame id
    const int n1 = tid & 15;                      // stage-1 role n1; stage-2 role k1
    const int fr = tid >> 4;                      // frame slot in block
    const int b  = g / N_FRAMES;
    const int f  = g - b * N_FRAMES;
    const float* __restrict__ xb = x + (size_t)b * T_LEN;

    // ---- load + window (reflect padding), n = n1 + 16*n2 ----
    float xw[16];
    const int base = f * HOP - HOP + n1;
    if (f >= 1 && f <= 4998) {
        const float* __restrict__ xp = xb + base;
#pragma unroll
        for (int n2 = 0; n2 < 16; ++n2) {
            xw[n2] = xp[16 * n2] * s_win[n1 + 16 * n2];
        }
    } else {
#pragma unroll
        for (int n2 = 0; n2 < 16; ++n2) {
            int j = base + 16 * n2;
            j = (j < 0) ? -j : j;
            j = (j >= T_LEN) ? (2 * T_LEN - 2 - j) : j;
            xw[n2] = xb[j] * s_win[n1 + 16 * n2];
        }
    }

    // ---- stage 1: real DFT-16 over n2, cos/sin folded (scalar v_fmac forms) ----
    float p[8], q[8];
#pragma unroll
    for (int n = 1; n <= 7; ++n) { p[n] = xw[n] + xw[16 - n]; q[n] = xw[n] - xw[16 - n]; }
    const float bse = xw[0] + xw[8];
    const float se  = p[2] + p[4] + p[6];
    const float so  = p[1] + p[3] + p[5] + p[7];
    const float r0  = bse + se + so;   // raw[0]
    const float r8  = bse + se - so;   // raw[8]
    float rre[8], rim[8];              // raw[k1], k1=1..7
#pragma unroll
    for (int k1 = 1; k1 <= 7; ++k1) {
        float re = xw[0] + ((k1 & 1) ? -xw[8] : xw[8]);
        float im = 0.f;
#pragma unroll
        for (int n = 1; n <= 7; ++n) {
            const int m = (k1 * n) & 15;
            re += p[n] * C16[m];
            im -= q[n] * S16[m];
        }
        rre[k1] = re;
        rim[k1] = im;
    }

    // ---- twiddle by e^{-2pi i n1 k1/256} (packed), write straight to LDS ----
    v2f* __restrict__ row = &s_c[fr][0];
    row[n1 * 17 + 0] = mk2(r0, 0.f);
#pragma unroll
    for (int k1 = 1; k1 <= 15; ++k1) {
        const float4 t = s_tw4[k1 * 16 + n1];
        const v2f T1 = mk2(t.x, t.y);  // (cos, -sin)
        const v2f T2 = mk2(t.z, t.w);  // (sin,  cos)
        v2f A;
        if (k1 < 8)       A = T1 * sp(rre[k1])      + T2 * sp(rim[k1]);
        else if (k1 == 8) A = T1 * sp(r8);
        else              A = T1 * sp(rre[16 - k1]) - T2 * sp(rim[16 - k1]);
        row[n1 * 17 + k1] = A;
    }
    __syncthreads();

    v2f bb[16];
#pragma unroll
    for (int m = 0; m < 16; ++m) bb[m] = row[m * 17 + n1];

    // ---- stage 2: radix-2 DIF FFT-16 (packed complex) ----
    // Stage A: span 8, twiddle W16^j on difference
#pragma unroll
    for (int j = 0; j < 8; ++j) {
        const v2f u = bb[j], v = bb[j + 8];
        bb[j] = u + v;
        const v2f d = u - v;
        v2f o;
        if      (j == 0) o = d;
        else if (j == 1) o = mk2( c1v, -s1v) * sp(d.x) + mk2(s1v,  c1v) * sp(d.y);
        else if (j == 2) o = mk2(d.x + d.y, d.y - d.x) * sp(R2);
        else if (j == 3) o = mk2( c3v, -s3v) * sp(d.x) + mk2(s3v,  c3v) * sp(d.y);
        else if (j == 4) o = mk2(d.y, -d.x);
        else if (j == 5) o = mk2(-c3v, -s3v) * sp(d.x) + mk2(s3v, -c3v) * sp(d.y);
        else if (j == 6) o = mk2(d.y - d.x, -(d.x + d.y)) * sp(R2);
        else             o = mk2(-c1v, -s1v) * sp(d.x) + mk2(s1v, -c1v) * sp(d.y);
        bb[j + 8] = o;
    }
    // Stage B: span 4, twiddles {1, R2(1-i), -i, R2(-1-i)}
#pragma unroll
    for (int h = 0; h <= 8; h += 8) {
#pragma unroll
        for (int j = 0; j < 4; ++j) {
            const v2f u = bb[h + j], v = bb[h + j + 4];
            bb[h + j] = u + v;
            const v2f d = u - v;
            v2f o;
            if      (j == 0) o = d;
            else if (j == 1) o = mk2(d.x + d.y, d.y - d.x) * sp(R2);
            else if (j == 2) o = mk2(d.y, -d.x);
            else             o = mk2(d.y - d.x, -(d.x + d.y)) * sp(R2);
            bb[h + j + 4] = o;
        }
    }
    // Stage C: span 2, twiddles {1, -i}
#pragma unroll
    for (int gg = 0; gg < 16; gg += 4) {
        {
            const v2f u = bb[gg], v = bb[gg + 2];
            bb[gg] = u + v;
            bb[gg + 2] = u - v;
        }
        {
            const v2f u = bb[gg + 1], v = bb[gg + 3];
            bb[gg + 1] = u + v;
            const v2f d = u - v;
            bb[gg + 3] = mk2(d.y, -d.x);
        }
    }
    // Stage D: even outputs only (bins k2=0..7); position 2t holds k2=bitrev3(t)
    constexpr int K2MAP[8] = {0, 4, 2, 6, 1, 5, 3, 7};
    float m2[8];
    float aws = 0.f;
#pragma unroll
    for (int t = 0; t < 8; ++t) {
        const v2f Y = bb[2 * t] + bb[2 * t + 1];
        m2[t] = Y.x * Y.x + Y.y * Y.y + 1e-14f;
        aws += s_aw[n1 + 16 * K2MAP[t]];
    }
    // paired logs: 8 -> 4 transcendentals (products bounded, no under/overflow)
    const float HALF_LN2 = 0.34657359027997264f; // v_log_f32 is log2
    const float lsum = __builtin_amdgcn_logf(m2[0] * m2[1])
                     + __builtin_amdgcn_logf(m2[2] * m2[3])
                     + __builtin_amdgcn_logf(m2[4] * m2[5])
                     + __builtin_amdgcn_logf(m2[6] * m2[7]);
    float ssum = HALF_LN2 * lsum + aws;

    // ---- bin 128: X[128] = sum_{n1} (-1)^{n1} * r0[n1] (real) ----
    float v = (n1 & 1) ? -r0 : r0;
    v += __shfl_xor(v, 1);
    v += __shfl_xor(v, 2);
    v += __shfl_xor(v, 4);
    v += __shfl_xor(v, 8);
    const float term128 = HALF_LN2 * __builtin_amdgcn_logf(v * v + 1e-14f) + s_aw[128];

    // ---- reduce 128 bins across the 16 lanes of this frame ----
    ssum += __shfl_xor(ssum, 1);
    ssum += __shfl_xor(ssum, 2);
    ssum += __shfl_xor(ssum, 4);
    ssum += __shfl_xor(ssum, 8);

    if (n1 == 0) out[g] = (ssum + term128) * (1.0f / 129.0f);
}

extern "C" void kernel_launch(void* const* d_in, const int* in_sizes, int n_in,
                              void* d_out, int out_size, void* d_ws, size_t ws_size,
                              hipStream_t stream) {
    const float* x = (const float*)d_in[0];
    float* out = (float*)d_out;
    loudness_kernel<<<TOTAL_FRAMES / FPB, 256, 0, stream>>>(x, out);
}

// Round 5
// 65.299 us; speedup vs baseline: 3.4151x; 1.1809x over previous
//
#include <hip/hip_runtime.h>
#include <math.h>

#define HOP 128
#define T_LEN 640000
#define N_FRAMES 5001
#define N_PAIRS 2501
#define NB 64
#define GPB 16   // pair-groups per block; 16 threads per group; 2 frames per group

typedef float v2f __attribute__((ext_vector_type(2)));

static __device__ __forceinline__ v2f mk2(float a, float b) { v2f r; r.x = a; r.y = b; return r; }
static __device__ __forceinline__ v2f sp(float s) { v2f r; r.x = s; r.y = s; return r; }

__global__ __launch_bounds__(256) void loudness_kernel(const float* __restrict__ x,
                                                       float* __restrict__ out) {
    constexpr float C16[16] = {
        1.0f,  0.9238795325112867f,  0.7071067811865476f,  0.3826834323650898f,
        0.0f, -0.3826834323650898f, -0.7071067811865476f, -0.9238795325112867f,
       -1.0f, -0.9238795325112867f, -0.7071067811865476f, -0.3826834323650898f,
        0.0f,  0.3826834323650898f,  0.7071067811865476f,  0.9238795325112867f};
    constexpr float S16[16] = {
        0.0f,  0.3826834323650898f,  0.7071067811865476f,  0.9238795325112867f,
        1.0f,  0.9238795325112867f,  0.7071067811865476f,  0.3826834323650898f,
        0.0f, -0.3826834323650898f, -0.7071067811865476f, -0.9238795325112867f,
       -1.0f, -0.9238795325112867f, -0.7071067811865476f, -0.3826834323650898f};
    const float R2  = 0.7071067811865476f;
    const float c1v = 0.9238795325112867f, s1v = 0.3826834323650898f;
    const float c3v = 0.3826834323650898f, s3v = 0.9238795325112867f;

    __shared__ float4 s_c[GPB][145];  // [g][w*9 + slot], 1 float4 pad/group  37120 B
    __shared__ float  s_winT[256];    // [n1][n2] = win[n1+16*n2]             1024 B
    __shared__ v2f    s_twP[256];     // [r][w] = (cos, -sin)(2pi r w/256)    2048 B
    __shared__ float  s_aw8[16];      // per-lane sum of 8 A-weights            64 B
    __shared__ float  s_aw128;

    const int tid = threadIdx.x;

    // ---- per-block table generation ----
    {
        const int hi = tid >> 4, lo = tid & 15;
        const float TP = 0.02454369260617026f; // 2*pi/256
        s_winT[tid] = 0.5f - 0.5f * cosf((float)(hi + 16 * lo) * TP);
        float s, c;
        sincosf((float)(hi * lo) * TP, &s, &c);
        s_twP[tid] = mk2(c, -s);
        if (tid < 129) {
            float fq = (float)tid * 62.5f;
            float f2 = fq * fq;
            const float a0 = 12194.217f * 12194.217f;
            const float a1 = 20.598997f * 20.598997f;
            const float a2 = 107.65265f * 107.65265f;
            const float a3 = 737.86223f * 737.86223f;
            float w = 2.0f + 20.0f * (log10f(a0) + 2.0f * log10f(fmaxf(f2, 1e-30f))
                     - log10f(f2 + a0) - log10f(f2 + a1)
                     - 0.5f * log10f(f2 + a2) - 0.5f * log10f(f2 + a3));
            ((float*)&s_c[0][0])[tid] = fmaxf(w, -80.0f); // scratch
        }
    }
    __syncthreads();
    if (tid < 16) {
        const float* scr = (const float*)&s_c[0][0];
        float s = 0.f;
#pragma unroll
        for (int k2 = 0; k2 < 8; ++k2) s += scr[tid + 16 * k2];
        s_aw8[tid] = s;
        if (tid == 0) s_aw128 = scr[128];
    }
    __syncthreads();

    const int g  = tid >> 4;   // pair-group in block
    const int r  = tid & 15;   // lane role: stage-1 n1; stage-2 k1
    const int gp = blockIdx.x * GPB + g;
    const int b  = gp / N_PAIRS;
    const int pp = gp - b * N_PAIRS;
    const int fA = 2 * pp;
    const int fB = (fA < 5000) ? fA + 1 : 5000;  // last pair duplicates frame 5000
    const int dB = (fB - fA) * HOP;              // 128 or 0
    const float* __restrict__ xb = x + (size_t)b * T_LEN;

    // ---- load + window, frames packed (A,B) in v2f ----
    v2f xw[16];
    const int base = fA * HOP - HOP + r;
    const float4* __restrict__ winr = (const float4*)&s_winT[r * 16];
    if (pp >= 1 && pp <= 2499) {
        const float* __restrict__ xp = xb + base;
#pragma unroll
        for (int c4 = 0; c4 < 4; ++c4) {
            const float4 wq = winr[c4];
            const int o = 64 * c4;
            xw[4 * c4 + 0] = mk2(xp[o +  0], xp[o +  0 + dB]) * sp(wq.x);
            xw[4 * c4 + 1] = mk2(xp[o + 16], xp[o + 16 + dB]) * sp(wq.y);
            xw[4 * c4 + 2] = mk2(xp[o + 32], xp[o + 32 + dB]) * sp(wq.z);
            xw[4 * c4 + 3] = mk2(xp[o + 48], xp[o + 48 + dB]) * sp(wq.w);
        }
    } else {
#pragma unroll
        for (int c4 = 0; c4 < 4; ++c4) {
            const float4 wq = winr[c4];
            const float wv[4] = {wq.x, wq.y, wq.z, wq.w};
#pragma unroll
            for (int e = 0; e < 4; ++e) {
                const int n2 = 4 * c4 + e;
                int jA = base + 16 * n2;
                int jB = jA + dB;
                jA = (jA < 0) ? -jA : jA;
                jA = (jA >= T_LEN) ? (2 * T_LEN - 2 - jA) : jA;
                jB = (jB < 0) ? -jB : jB;
                jB = (jB >= T_LEN) ? (2 * T_LEN - 2 - jB) : jB;
                xw[n2] = mk2(xb[jA], xb[jB]) * sp(wv[e]);
            }
        }
    }

    // ---- stage 1: real DFT-16 over n2 (both frames packed), Hermitian compact ----
    v2f p[8], q[8];
#pragma unroll
    for (int n = 1; n <= 7; ++n) { p[n] = xw[n] + xw[16 - n]; q[n] = xw[n] - xw[16 - n]; }
    const v2f bse = xw[0] + xw[8];
    const v2f d08 = xw[0] - xw[8];
    const v2f se  = p[2] + p[4] + p[6];
    const v2f so  = p[1] + p[3] + p[5] + p[7];
    const v2f r0  = bse + se + so;
    const v2f r8  = bse + se - so;
    v2f rre[8], rim[8];
#pragma unroll
    for (int k1 = 1; k1 <= 7; ++k1) {
        v2f re = (k1 & 1) ? d08 : bse;
        v2f im = sp(0.f);
#pragma unroll
        for (int n = 1; n <= 7; ++n) {
            const int m = (k1 * n) & 15;
            re += p[n] * sp(C16[m]);
            im -= q[n] * sp(S16[m]);
        }
        rre[k1] = re;
        rim[k1] = im;
    }

    // ---- write raw Hermitian-compact spectrum: 9 float4 slots (reA,reB,imA,imB) ----
    float4* __restrict__ myrow = &s_c[g][r * 9];
    myrow[0] = make_float4(r0.x, r0.y, 0.f, 0.f);
#pragma unroll
    for (int k = 1; k <= 7; ++k)
        myrow[k] = make_float4(rre[k].x, rre[k].y, rim[k].x, rim[k].y);
    myrow[8] = make_float4(r8.x, r8.y, 0.f, 0.f);
    __syncthreads();

    // ---- read column (transpose) + reader-side twiddle tw(r,w) ----
    const int rp = (r <= 8) ? r : 16 - r;
    const v2f sgnv = sp((r <= 8) ? 1.f : -1.f);   // conj for r>8
    const v2f* __restrict__ twr = &s_twP[r * 16];
    const float4* __restrict__ col = &s_c[g][rp];
    v2f bbx[16], bby[16];
#pragma unroll
    for (int w = 0; w < 16; ++w) {
        const float4 fv = col[w * 9];
        const v2f xx = mk2(fv.x, fv.y);
        const v2f yy = mk2(fv.z, fv.w) * sgnv;
        const v2f t = twr[w];                      // (c, -s)
        bbx[w] = xx * sp(t.x) - yy * sp(t.y);
        bby[w] = xx * sp(t.y) + yy * sp(t.x);
    }

    // ---- stage 2: radix-2 DIF FFT-16 over w, re/im separated, frames packed ----
    // Stage A: span 8, twiddle W16^j on difference
#pragma unroll
    for (int j = 0; j < 8; ++j) {
        const v2f ux = bbx[j], uy = bby[j], vx = bbx[j + 8], vy = bby[j + 8];
        bbx[j] = ux + vx; bby[j] = uy + vy;
        const v2f dx = ux - vx, dy = uy - vy;
        v2f ox, oy;
        if      (j == 0) { ox = dx;                              oy = dy; }
        else if (j == 1) { ox =  dx * sp(c1v) + dy * sp(s1v);    oy =  dy * sp(c1v) - dx * sp(s1v); }
        else if (j == 2) { ox = (dx + dy) * sp(R2);              oy = (dy - dx) * sp(R2); }
        else if (j == 3) { ox =  dx * sp(c3v) + dy * sp(s3v);    oy =  dy * sp(c3v) - dx * sp(s3v); }
        else if (j == 4) { ox = dy;                              oy = sp(0.f) - dx; }
        else if (j == 5) { ox = dy * sp(s3v) - dx * sp(c3v);     oy = sp(0.f) - dy * sp(c3v) - dx * sp(s3v); }
        else if (j == 6) { ox = (dy - dx) * sp(R2);              oy = sp(0.f) - (dx + dy) * sp(R2); }
        else             { ox = dy * sp(s1v) - dx * sp(c1v);     oy = sp(0.f) - dy * sp(c1v) - dx * sp(s1v); }
        bbx[j + 8] = ox; bby[j + 8] = oy;
    }
    // Stage B: span 4, twiddles {1, R2(1-i), -i, R2(-1-i)}
#pragma unroll
    for (int h = 0; h <= 8; h += 8) {
#pragma unroll
        for (int j = 0; j < 4; ++j) {
            const v2f ux = bbx[h + j], uy = bby[h + j], vx = bbx[h + j + 4], vy = bby[h + j + 4];
            bbx[h + j] = ux + vx; bby[h + j] = uy + vy;
            const v2f dx = ux - vx, dy = uy - vy;
            v2f ox, oy;
            if      (j == 0) { ox = dx;                  oy = dy; }
            else if (j == 1) { ox = (dx + dy) * sp(R2);  oy = (dy - dx) * sp(R2); }
            else if (j == 2) { ox = dy;                  oy = sp(0.f) - dx; }
            else             { ox = (dy - dx) * sp(R2);  oy = sp(0.f) - (dx + dy) * sp(R2); }
            bbx[h + j + 4] = ox; bby[h + j + 4] = oy;
        }
    }
    // Stage C: span 2, twiddles {1, -i}
#pragma unroll
    for (int gg = 0; gg < 16; gg += 4) {
        {
            const v2f ux = bbx[gg], uy = bby[gg], vx = bbx[gg + 2], vy = bby[gg + 2];
            bbx[gg] = ux + vx;     bby[gg] = uy + vy;
            bbx[gg + 2] = ux - vx; bby[gg + 2] = uy - vy;
        }
        {
            const v2f ux = bbx[gg + 1], uy = bby[gg + 1], vx = bbx[gg + 3], vy = bby[gg + 3];
            bbx[gg + 1] = ux + vx; bby[gg + 1] = uy + vy;
            const v2f dx = ux - vx, dy = uy - vy;
            bbx[gg + 3] = dy; bby[gg + 3] = sp(0.f) - dx;
        }
    }

    // ---- stage D: even outputs (bins r+16*k2, k2=0..7) + paired logs ----
    const float HALF_LN2 = 0.34657359027997264f; // v_log_f32 is log2
    v2f m2[8];
#pragma unroll
    for (int t = 0; t < 8; ++t) {
        const v2f Yx = bbx[2 * t] + bbx[2 * t + 1];
        const v2f Yy = bby[2 * t] + bby[2 * t + 1];
        m2[t] = Yx * Yx + Yy * Yy + sp(1e-14f);
    }
    const v2f P0 = m2[0] * m2[1], P1 = m2[2] * m2[3], P2 = m2[4] * m2[5], P3 = m2[6] * m2[7];
    const float lA = __builtin_amdgcn_logf(P0.x) + __builtin_amdgcn_logf(P1.x)
                   + __builtin_amdgcn_logf(P2.x) + __builtin_amdgcn_logf(P3.x);
    const float lB = __builtin_amdgcn_logf(P0.y) + __builtin_amdgcn_logf(P1.y)
                   + __builtin_amdgcn_logf(P2.y) + __builtin_amdgcn_logf(P3.y);
    v2f ssum = sp(HALF_LN2) * mk2(lA, lB) + sp(s_aw8[r]);

    // ---- bin 128 from lane 0's odd FFT output: Y[8] = p0 - p1 (real) ----
    const v2f d0 = bbx[0] - bbx[1];
    if (r == 0) {
        ssum += sp(HALF_LN2) * mk2(__builtin_amdgcn_logf(d0.x * d0.x + 1e-14f),
                                   __builtin_amdgcn_logf(d0.y * d0.y + 1e-14f))
              + sp(s_aw128);
    }

    // ---- reduce across the 16 lanes of this group ----
    ssum.x += __shfl_xor(ssum.x, 1); ssum.y += __shfl_xor(ssum.y, 1);
    ssum.x += __shfl_xor(ssum.x, 2); ssum.y += __shfl_xor(ssum.y, 2);
    ssum.x += __shfl_xor(ssum.x, 4); ssum.y += __shfl_xor(ssum.y, 4);
    ssum.x += __shfl_xor(ssum.x, 8); ssum.y += __shfl_xor(ssum.y, 8);

    if (r == 0) {
        out[b * N_FRAMES + fA] = ssum.x * (1.0f / 129.0f);
        out[b * N_FRAMES + fB] = ssum.y * (1.0f / 129.0f);  // dup pair: same addr, same value
    }
}

extern "C" void kernel_launch(void* const* d_in, const int* in_sizes, int n_in,
                              void* d_out, int out_size, void* d_ws, size_t ws_size,
                              hipStream_t stream) {
    const float* x = (const float*)d_in[0];
    float* out = (float*)d_out;
    loudness_kernel<<<(NB * N_PAIRS) / GPB, 256, 0, stream>>>(x, out);
}

// Round 6
// 57.138 us; speedup vs baseline: 3.9028x; 1.1428x over previous
//
#include <hip/hip_runtime.h>
#include <math.h>

#define HOP 128
#define T_LEN 640000
#define N_FRAMES 5001
#define N_PAIRS 2501
#define NB 64
#define GPB 16   // pair-groups per block; 16 threads per group; 2 frames per group

// LDS geometry (v2f units)
#define RE_SLOT 18
#define RE_GRP  160   // 8*18+16
#define IM_SLOT 18
#define IM_GRP  142   // 7*18+16  (8 slots: slot0 = zeros, slots 1..7 = data)

typedef float v2f __attribute__((ext_vector_type(2)));

static __device__ __forceinline__ v2f mk2(float a, float b) { v2f r; r.x = a; r.y = b; return r; }
static __device__ __forceinline__ v2f sp(float s) { v2f r; r.x = s; r.y = s; return r; }

// 16-lane sum reduction via DPP (no LDS traffic); groups are 16-lane aligned.
static __device__ __forceinline__ float rsum16(float v) {
    v += __int_as_float(__builtin_amdgcn_update_dpp(0, __float_as_int(v), 0xB1, 0xF, 0xF, true));  // quad_perm [1,0,3,2]
    v += __int_as_float(__builtin_amdgcn_update_dpp(0, __float_as_int(v), 0x4E, 0xF, 0xF, true));  // quad_perm [2,3,0,1]
    v += __int_as_float(__builtin_amdgcn_update_dpp(0, __float_as_int(v), 0x141, 0xF, 0xF, true)); // row_half_mirror
    v += __int_as_float(__builtin_amdgcn_update_dpp(0, __float_as_int(v), 0x140, 0xF, 0xF, true)); // row_mirror
    return v;
}

__global__ __launch_bounds__(256) void loudness_kernel(const float* __restrict__ x,
                                                       float* __restrict__ out) {
    constexpr float C16[16] = {
        1.0f,  0.9238795325112867f,  0.7071067811865476f,  0.3826834323650898f,
        0.0f, -0.3826834323650898f, -0.7071067811865476f, -0.9238795325112867f,
       -1.0f, -0.9238795325112867f, -0.7071067811865476f, -0.3826834323650898f,
        0.0f,  0.3826834323650898f,  0.7071067811865476f,  0.9238795325112867f};
    constexpr float S16[16] = {
        0.0f,  0.3826834323650898f,  0.7071067811865476f,  0.9238795325112867f,
        1.0f,  0.9238795325112867f,  0.7071067811865476f,  0.3826834323650898f,
        0.0f, -0.3826834323650898f, -0.7071067811865476f, -0.9238795325112867f,
       -1.0f, -0.9238795325112867f, -0.7071067811865476f, -0.3826834323650898f};
    const float R2  = 0.7071067811865476f;
    const float c1v = 0.9238795325112867f, s1v = 0.3826834323650898f;
    const float c3v = 0.3826834323650898f, s3v = 0.9238795325112867f;
    const float CP8 = 0.9238795325112867f, SP8 = 0.3826834323650898f;
    const float K2  = 1.8477590650225735f; // 2*cos(pi/8)

    __shared__ alignas(16) v2f s_re[16 * RE_GRP];  // 20480 B
    __shared__ alignas(16) v2f s_im[16 * IM_GRP];  // 18176 B
    __shared__ v2f   s_stp[16];                    //   128 B : (cos, -sin)(2pi r/256)
    __shared__ float s_aw8[16];                    //    64 B
    __shared__ float s_aw128;

    const int tid = threadIdx.x;

    // ---- per-block table generation ----
    {
        const float TP = 0.02454369260617026f; // 2*pi/256
        if (tid < 16) {
            float s, c;
            sincosf((float)tid * TP, &s, &c);
            s_stp[tid] = mk2(c, -s);
        }
        if (tid < 129) {
            float fq = (float)tid * 62.5f;
            float f2 = fq * fq;
            const float a0 = 12194.217f * 12194.217f;
            const float a1 = 20.598997f * 20.598997f;
            const float a2 = 107.65265f * 107.65265f;
            const float a3 = 737.86223f * 737.86223f;
            float w = 2.0f + 20.0f * (log10f(a0) + 2.0f * log10f(fmaxf(f2, 1e-30f))
                     - log10f(f2 + a0) - log10f(f2 + a1)
                     - 0.5f * log10f(f2 + a2) - 0.5f * log10f(f2 + a3));
            ((float*)&s_im[0])[tid] = fmaxf(w, -80.0f); // scratch in s_im
        }
    }
    __syncthreads();
    if (tid < 16) {
        const float* scr = (const float*)&s_im[0];
        float s = 0.f;
#pragma unroll
        for (int k2 = 0; k2 < 8; ++k2) s += scr[tid + 16 * k2];
        s_aw8[tid] = s;
        if (tid == 0) s_aw128 = scr[128];
    }
    __syncthreads();
    // zero im slot 0 (Hermitian zeros; rp==0 and rp==8 both read it)
    s_im[(tid >> 4) * IM_GRP + (tid & 15)] = sp(0.f);
    __syncthreads();

    const int g  = tid >> 4;   // pair-group in block (one wave holds groups 4w..4w+3)
    const int r  = tid & 15;   // lane role: stage-1 n1; stage-2 k1
    const int gp = blockIdx.x * GPB + g;
    const int b  = gp / N_PAIRS;
    const int pp = gp - b * N_PAIRS;
    const int fA = 2 * pp;
    const int fB = (fA < 5000) ? fA + 1 : 5000;  // last pair duplicates frame 5000
    const int dB = (fB - fA) * HOP;              // 128 or 0
    const float* __restrict__ xb = x + (size_t)b * T_LEN;

    // ---- window via Chebyshev recurrence: win(n2) = 0.5 - 0.5*cos(th_r + n2*pi/8) ----
    const v2f stp = s_stp[r];                    // (cos th, -sin th)
    float win16[16];
    {
        float cm2 = stp.x;                       // cos(th)
        float cm1 = stp.x * CP8 + stp.y * SP8;   // cos(th + pi/8)
        win16[0] = 0.5f - 0.5f * cm2;
        win16[1] = 0.5f - 0.5f * cm1;
#pragma unroll
        for (int n = 2; n < 16; ++n) {
            const float c = K2 * cm1 - cm2;
            win16[n] = 0.5f - 0.5f * c;
            cm2 = cm1; cm1 = c;
        }
    }

    // ---- load + window, frames packed (A,B) in v2f ----
    v2f xw[16];
    const int base = fA * HOP - HOP + r;
    if (pp >= 1 && pp <= 2499) {
        const float* __restrict__ xp = xb + base;
#pragma unroll
        for (int n2 = 0; n2 < 16; ++n2) {
            const int o = 16 * n2;
            xw[n2] = mk2(xp[o], xp[o + dB]) * sp(win16[n2]);
        }
    } else {
#pragma unroll
        for (int n2 = 0; n2 < 16; ++n2) {
            int jA = base + 16 * n2;
            int jB = jA + dB;
            jA = (jA < 0) ? -jA : jA;
            jA = (jA >= T_LEN) ? (2 * T_LEN - 2 - jA) : jA;
            jB = (jB < 0) ? -jB : jB;
            jB = (jB >= T_LEN) ? (2 * T_LEN - 2 - jB) : jB;
            xw[n2] = mk2(xb[jA], xb[jB]) * sp(win16[n2]);
        }
    }

    // ---- stage 1: real DFT-16 over n2 (frames packed), Hermitian compact ----
    v2f p[8], q[8];
#pragma unroll
    for (int n = 1; n <= 7; ++n) { p[n] = xw[n] + xw[16 - n]; q[n] = xw[n] - xw[16 - n]; }
    const v2f bse = xw[0] + xw[8];
    const v2f d08 = xw[0] - xw[8];
    const v2f se  = p[2] + p[4] + p[6];
    const v2f so  = p[1] + p[3] + p[5] + p[7];
    const v2f r0  = bse + se + so;
    const v2f r8  = bse + se - so;
    v2f rre[8], rim[8];
#pragma unroll
    for (int k1 = 1; k1 <= 7; ++k1) {
        v2f re = (k1 & 1) ? d08 : bse;
        v2f im = sp(0.f);
#pragma unroll
        for (int n = 1; n <= 7; ++n) {
            const int m = (k1 * n) & 15;
            re += p[n] * sp(C16[m]);
            im -= q[n] * sp(S16[m]);
        }
        rre[k1] = re;
        rim[k1] = im;
    }

    // ---- write Hermitian-compact spectrum, slot-major (conflict-free b64) ----
    {
        v2f* __restrict__ reW = &s_re[g * RE_GRP + r];  // this lane is writer w=r
        v2f* __restrict__ imW = &s_im[g * IM_GRP + r];
        reW[0] = r0;
#pragma unroll
        for (int k = 1; k <= 7; ++k) {
            reW[RE_SLOT * k] = rre[k];
            imW[IM_SLOT * k] = rim[k];
        }
        reW[RE_SLOT * 8] = r8;
    }
    // groups are intra-wave (16 lanes within one wave64): no barrier needed,
    // compiler inserts lgkmcnt for the LDS RAW hazard.

    // ---- read column (transpose, b128 = two w's) + reader-side twiddle recurrence ----
    const int rp  = (r <= 8) ? r : 16 - r;
    const int rp7 = rp & 7;                       // im: rp==8 -> zero slot 0
    const v2f sgnv = sp((r <= 8) ? 1.f : -1.f);   // conj for r>8
    const float4* __restrict__ reCol = (const float4*)&s_re[g * RE_GRP + RE_SLOT * rp];
    const float4* __restrict__ imCol = (const float4*)&s_im[g * IM_GRP + IM_SLOT * rp7];

    v2f bbx[16], bby[16];
    float tc = 1.f, tms = 0.f;                    // e^{-i th r w}, w=0
    const float sc = stp.x, sms = stp.y;
#pragma unroll
    for (int j = 0; j < 8; ++j) {
        const float4 R4v = reCol[j];
        const float4 I4v = imCol[j];
        // w = 2j
        {
            const v2f xx = mk2(R4v.x, R4v.y);
            const v2f yy = mk2(I4v.x, I4v.y) * sgnv;
            if (j == 0) { bbx[0] = xx; bby[0] = yy; }
            else {
                bbx[2 * j] = xx * sp(tc) - yy * sp(tms);
                bby[2 * j] = xx * sp(tms) + yy * sp(tc);
            }
            const float ntc = tc * sc - tms * sms;
            const float nts = tc * sms + tms * sc;
            tc = ntc; tms = nts;
        }
        // w = 2j+1
        {
            const v2f xx = mk2(R4v.z, R4v.w);
            const v2f yy = mk2(I4v.z, I4v.w) * sgnv;
            bbx[2 * j + 1] = xx * sp(tc) - yy * sp(tms);
            bby[2 * j + 1] = xx * sp(tms) + yy * sp(tc);
            if (j < 7) {
                const float ntc = tc * sc - tms * sms;
                const float nts = tc * sms + tms * sc;
                tc = ntc; tms = nts;
            }
        }
    }

    // ---- stage 2: radix-2 DIF FFT-16 over w, re/im separated, frames packed ----
#pragma unroll
    for (int j = 0; j < 8; ++j) {
        const v2f ux = bbx[j], uy = bby[j], vx = bbx[j + 8], vy = bby[j + 8];
        bbx[j] = ux + vx; bby[j] = uy + vy;
        const v2f dx = ux - vx, dy = uy - vy;
        v2f ox, oy;
        if      (j == 0) { ox = dx;                              oy = dy; }
        else if (j == 1) { ox =  dx * sp(c1v) + dy * sp(s1v);    oy =  dy * sp(c1v) - dx * sp(s1v); }
        else if (j == 2) { ox = (dx + dy) * sp(R2);              oy = (dy - dx) * sp(R2); }
        else if (j == 3) { ox =  dx * sp(c3v) + dy * sp(s3v);    oy =  dy * sp(c3v) - dx * sp(s3v); }
        else if (j == 4) { ox = dy;                              oy = sp(0.f) - dx; }
        else if (j == 5) { ox = dy * sp(s3v) - dx * sp(c3v);     oy = sp(0.f) - dy * sp(c3v) - dx * sp(s3v); }
        else if (j == 6) { ox = (dy - dx) * sp(R2);              oy = sp(0.f) - (dx + dy) * sp(R2); }
        else             { ox = dy * sp(s1v) - dx * sp(c1v);     oy = sp(0.f) - dy * sp(c1v) - dx * sp(s1v); }
        bbx[j + 8] = ox; bby[j + 8] = oy;
    }
#pragma unroll
    for (int h = 0; h <= 8; h += 8) {
#pragma unroll
        for (int j = 0; j < 4; ++j) {
            const v2f ux = bbx[h + j], uy = bby[h + j], vx = bbx[h + j + 4], vy = bby[h + j + 4];
            bbx[h + j] = ux + vx; bby[h + j] = uy + vy;
            const v2f dx = ux - vx, dy = uy - vy;
            v2f ox, oy;
            if      (j == 0) { ox = dx;                  oy = dy; }
            else if (j == 1) { ox = (dx + dy) * sp(R2);  oy = (dy - dx) * sp(R2); }
            else if (j == 2) { ox = dy;                  oy = sp(0.f) - dx; }
            else             { ox = (dy - dx) * sp(R2);  oy = sp(0.f) - (dx + dy) * sp(R2); }
            bbx[h + j + 4] = ox; bby[h + j + 4] = oy;
        }
    }
#pragma unroll
    for (int gg = 0; gg < 16; gg += 4) {
        {
            const v2f ux = bbx[gg], uy = bby[gg], vx = bbx[gg + 2], vy = bby[gg + 2];
            bbx[gg] = ux + vx;     bby[gg] = uy + vy;
            bbx[gg + 2] = ux - vx; bby[gg + 2] = uy - vy;
        }
        {
            const v2f ux = bbx[gg + 1], uy = bby[gg + 1], vx = bbx[gg + 3], vy = bby[gg + 3];
            bbx[gg + 1] = ux + vx; bby[gg + 1] = uy + vy;
            const v2f dx = ux - vx, dy = uy - vy;
            bbx[gg + 3] = dy; bby[gg + 3] = sp(0.f) - dx;
        }
    }

    // ---- stage D: even outputs (bins r+16*k2) + paired logs ----
    const float HALF_LN2 = 0.34657359027997264f; // v_log_f32 is log2
    v2f m2[8];
#pragma unroll
    for (int t = 0; t < 8; ++t) {
        const v2f Yx = bbx[2 * t] + bbx[2 * t + 1];
        const v2f Yy = bby[2 * t] + bby[2 * t + 1];
        m2[t] = Yx * Yx + Yy * Yy + sp(1e-14f);
    }
    const v2f P0 = m2[0] * m2[1], P1 = m2[2] * m2[3], P2 = m2[4] * m2[5], P3 = m2[6] * m2[7];
    const float lA = __builtin_amdgcn_logf(P0.x) + __builtin_amdgcn_logf(P1.x)
                   + __builtin_amdgcn_logf(P2.x) + __builtin_amdgcn_logf(P3.x);
    const float lB = __builtin_amdgcn_logf(P0.y) + __builtin_amdgcn_logf(P1.y)
                   + __builtin_amdgcn_logf(P2.y) + __builtin_amdgcn_logf(P3.y);
    v2f ssum = sp(HALF_LN2) * mk2(lA, lB) + sp(s_aw8[r]);

    // ---- bin 128 from lane 0's odd FFT output: Y[8] = pos0 - pos1 (real) ----
    const v2f d0 = bbx[0] - bbx[1];
    if (r == 0) {
        ssum += sp(HALF_LN2) * mk2(__builtin_amdgcn_logf(d0.x * d0.x + 1e-14f),
                                   __builtin_amdgcn_logf(d0.y * d0.y + 1e-14f))
              + sp(s_aw128);
    }

    // ---- reduce across the 16 lanes of this group (DPP, no LDS) ----
    ssum.x = rsum16(ssum.x);
    ssum.y = rsum16(ssum.y);

    if (r == 0) {
        out[b * N_FRAMES + fA] = ssum.x * (1.0f / 129.0f);
        out[b * N_FRAMES + fB] = ssum.y * (1.0f / 129.0f);  // dup pair: same addr, same value
    }
}

extern "C" void kernel_launch(void* const* d_in, const int* in_sizes, int n_in,
                              void* d_out, int out_size, void* d_ws, size_t ws_size,
                              hipStream_t stream) {
    const float* x = (const float*)d_in[0];
    float* out = (float*)d_out;
    loudness_kernel<<<(NB * N_PAIRS) / GPB, 256, 0, stream>>>(x, out);
}